// Round 2
// baseline (216.162 us; speedup 1.0000x reference)
//
#include <hip/hip_runtime.h>

#define LAMBDA_COORD 5.0f
#define LAMBDA_NOOBJ 0.5f
#define WH_EPS 1e-6f
#define IOU_EPS 1e-6f

// Register-direct design: each lane owns a PAIR of adjacent cells.
// A cell is 30 floats = 120 B; a pair is 240 B = 15 aligned float4.
// -> per-lane global_load_dwordx4, all 16-B aligned, no LDS staging at all.
// The wave's per-iteration footprint (64 lanes x 240 B x 2 arrays = 30 KB,
// contiguous) is fully consumed, so L1/L2 absorb the intra-wave stride.
// Occupancy cap moves from LDS (5 waves/CU) to VGPRs (~12 waves/CU) and
// each wave can keep ~30 loads in flight -> ~4x the memory-level parallelism.

constexpr int THREADS = 256;

__device__ __forceinline__ float iou_yolo(float a0, float a1, float a2, float a3,
                                          float b0, float b1, float b2, float b3) {
    float ax1 = a0 - a2 * 0.5f, ay1 = a1 - a3 * 0.5f;
    float ax2 = a0 + a2 * 0.5f, ay2 = a1 + a3 * 0.5f;
    float bx1 = b0 - b2 * 0.5f, by1 = b1 - b3 * 0.5f;
    float bx2 = b0 + b2 * 0.5f, by2 = b1 + b3 * 0.5f;
    float iw = fmaxf(fminf(ax2, bx2) - fmaxf(ax1, bx1), 0.0f);
    float ih = fmaxf(fminf(ay2, by2) - fmaxf(ay1, by1), 0.0f);
    float inter = iw * ih;
    float area_a = fabsf((ax2 - ax1) * (ay2 - ay1));
    float area_b = fabsf((bx2 - bx1) * (by2 - by1));
    return inter / (area_a + area_b - inter + IOU_EPS);
}

// Full loss for one cell; t/p point at 30 consecutive floats in REGISTERS
// (all indices compile-time constant after inlining -> SROA keeps them in VGPRs).
__device__ __forceinline__ float cell_loss(const float* t, const float* p) {
    const float b0 = t[0], b1 = t[1], b2 = t[2], b3 = t[3], t4 = t[4];

    float iou1 = iou_yolo(b0, b1, b2, b3, p[0], p[1], p[2], p[3]);
    float iou2 = iou_yolo(b0, b1, b2, b3, p[5], p[6], p[7], p[8]);
    bool use1 = iou1 > iou2;

    float bh0 = use1 ? p[0] : p[5];
    float bh1 = use1 ? p[1] : p[6];
    float bh2 = use1 ? p[2] : p[7];
    float bh3 = use1 ? p[3] : p[8];
    float conf_c = use1 ? p[4] : p[9];
    float conf_o = use1 ? p[9] : p[4];

    float dx = b0 - bh0, dy = b1 - bh1;
    float xy = LAMBDA_COORD * (dx * dx + dy * dy);

    float sw = sqrtf(b2) - sqrtf(fabsf(bh2 + WH_EPS));
    float sh = sqrtf(b3) - sqrtf(fabsf(bh3 + WH_EPS));
    float wh = LAMBDA_COORD * (sw * sw + sh * sh);

    float dc = t4 - conf_c;
    float obj_conf = dc * dc;
    float noobj_in_obj = LAMBDA_NOOBJ * conf_o * conf_o;

    float cls = 0.0f;
#pragma unroll
    for (int k = 10; k < 30; ++k) {
        float d = t[k] - p[k];
        cls += d * d;
    }

    float obj_terms = xy + wh + obj_conf + noobj_in_obj + cls;

    float d4 = t4 - p[4], d9 = t4 - p[9];
    float noobj_terms = LAMBDA_NOOBJ * (d4 * d4 + d9 * d9);

    return (t4 == 1.0f) ? obj_terms : noobj_terms;
}

// __launch_bounds__(256, 3): 3 blocks/CU = 12 waves/CU target, VGPR cap ~170.
__global__ __launch_bounds__(THREADS, 3) void yolo_loss_main(
    const float4* __restrict__ tv, const float4* __restrict__ pv,
    float* __restrict__ ws, int npairs) {
    const int stride = gridDim.x * THREADS;
    float v = 0.0f;

    for (int pair = blockIdx.x * THREADS + threadIdx.x; pair < npairs; pair += stride) {
        const float4* tg = tv + (size_t)pair * 15;
        const float4* pg = pv + (size_t)pair * 15;
        float4 tb[15], pb[15];
#pragma unroll
        for (int j = 0; j < 15; ++j) tb[j] = tg[j];
#pragma unroll
        for (int j = 0; j < 15; ++j) pb[j] = pg[j];
        const float* tf = (const float*)tb;
        const float* pf = (const float*)pb;
        // cell A = floats [0,30), cell B = floats [30,60) of the pair
        v += cell_loss(tf, pf) + cell_loss(tf + 30, pf + 30);
    }

    // wave64 reduction
#pragma unroll
    for (int off = 32; off > 0; off >>= 1)
        v += __shfl_down(v, off, 64);

    // block reduction -> one PLAIN store per block (no same-address atomics:
    // the old kernel's 1280 end-of-kernel atomicAdds serialize at one L2 bank)
    __shared__ float part[THREADS / 64];
    if ((threadIdx.x & 63) == 0) part[threadIdx.x >> 6] = v;
    __syncthreads();
    if (threadIdx.x == 0) {
        float s = 0.0f;
#pragma unroll
        for (int w = 0; w < THREADS / 64; ++w) s += part[w];
        ws[blockIdx.x] = s;
    }
}

__global__ __launch_bounds__(256) void yolo_loss_finish(
    const float* __restrict__ ws, float* __restrict__ out,
    int nblocks, float inv_batch) {
    float v = 0.0f;
    for (int i = threadIdx.x; i < nblocks; i += 256) v += ws[i];
#pragma unroll
    for (int off = 32; off > 0; off >>= 1)
        v += __shfl_down(v, off, 64);
    __shared__ float part[4];
    if ((threadIdx.x & 63) == 0) part[threadIdx.x >> 6] = v;
    __syncthreads();
    if (threadIdx.x == 0)
        out[0] = (part[0] + part[1] + part[2] + part[3]) * inv_batch;
}

extern "C" void kernel_launch(void* const* d_in, const int* in_sizes, int n_in,
                              void* d_out, int out_size, void* d_ws, size_t ws_size,
                              hipStream_t stream) {
    const float* t = (const float*)d_in[0];  // y_trues
    const float* p = (const float*)d_in[1];  // y_preds
    float* out = (float*)d_out;
    float* ws = (float*)d_ws;

    const int total = in_sizes[0];            // 24,084,480 floats
    const int cells = total / 30;             // 802,816 (even -> pairs exact)
    const int npairs = cells / 2;             // 401,408
    const int batch = cells / 49;             // 16,384
    const float inv_batch = 1.0f / (float)batch;

    // 2 pairs per thread: 784 blocks x 256 threads x 2 = 401,408 exactly.
    const int blocks = (npairs + THREADS * 2 - 1) / (THREADS * 2);

    yolo_loss_main<<<blocks, THREADS, 0, stream>>>(
        (const float4*)t, (const float4*)p, ws, npairs);
    // d_out is poisoned before every replay; finisher overwrites it (no memset needed).
    yolo_loss_finish<<<1, 256, 0, stream>>>(ws, out, blocks, inv_batch);
}

// Round 3
// 209.475 us; speedup vs baseline: 1.0319x; 1.0319x over previous
//
#include <hip/hip_runtime.h>

#define LAMBDA_COORD 5.0f
#define LAMBDA_NOOBJ 0.5f
#define WH_EPS 1e-6f
#define IOU_EPS 1e-6f

// Round-3 design: ONE cell-pair per thread, NO loop, HIGH VGPR budget.
//
// Round-2 post-mortem: VGPR_Count=68 proved the compiler never held the
// 30 float4 loads in flight (needs 120 VGPRs) — it serialized into small
// load->waitcnt->use clusters to fit the (256,3) budget, so each wave had
// only a few outstanding loads and the kernel was pure latency exposure
// (VALUBusy 5%, 197k cycles for 753 KB/CU).
//
// This version removes both causes:
//  - no grid-stride loop: 401,408 pairs = 1568 blocks x 256 threads exactly,
//    so all 30 loads are independent straight-line code issued before any use;
//  - __launch_bounds__(256, 2): VGPR cap 256 -> payload fits in registers,
//    2 blocks/CU = 8 waves/CU resident; grid = 6.1 blocks/CU keeps CUs fed.
// Expected emitted shape: 30x global_load_dwordx4, one s_waitcnt region,
// ~600 VALU cycles, per-wave outstanding bytes = 30 KB -> ~240 KB/CU in flight.

constexpr int THREADS = 256;

__device__ __forceinline__ float iou_yolo(float a0, float a1, float a2, float a3,
                                          float b0, float b1, float b2, float b3) {
    float ax1 = a0 - a2 * 0.5f, ay1 = a1 - a3 * 0.5f;
    float ax2 = a0 + a2 * 0.5f, ay2 = a1 + a3 * 0.5f;
    float bx1 = b0 - b2 * 0.5f, by1 = b1 - b3 * 0.5f;
    float bx2 = b0 + b2 * 0.5f, by2 = b1 + b3 * 0.5f;
    float iw = fmaxf(fminf(ax2, bx2) - fmaxf(ax1, bx1), 0.0f);
    float ih = fmaxf(fminf(ay2, by2) - fmaxf(ay1, by1), 0.0f);
    float inter = iw * ih;
    float area_a = fabsf((ax2 - ax1) * (ay2 - ay1));
    float area_b = fabsf((bx2 - bx1) * (by2 - by1));
    return inter / (area_a + area_b - inter + IOU_EPS);
}

// Full loss for one cell; t/p point at 30 consecutive floats in registers
// (constant indices after inlining -> SROA).
__device__ __forceinline__ float cell_loss(const float* t, const float* p) {
    const float b0 = t[0], b1 = t[1], b2 = t[2], b3 = t[3], t4 = t[4];

    float iou1 = iou_yolo(b0, b1, b2, b3, p[0], p[1], p[2], p[3]);
    float iou2 = iou_yolo(b0, b1, b2, b3, p[5], p[6], p[7], p[8]);
    bool use1 = iou1 > iou2;

    float bh0 = use1 ? p[0] : p[5];
    float bh1 = use1 ? p[1] : p[6];
    float bh2 = use1 ? p[2] : p[7];
    float bh3 = use1 ? p[3] : p[8];
    float conf_c = use1 ? p[4] : p[9];
    float conf_o = use1 ? p[9] : p[4];

    float dx = b0 - bh0, dy = b1 - bh1;
    float xy = LAMBDA_COORD * (dx * dx + dy * dy);

    float sw = sqrtf(b2) - sqrtf(fabsf(bh2 + WH_EPS));
    float sh = sqrtf(b3) - sqrtf(fabsf(bh3 + WH_EPS));
    float wh = LAMBDA_COORD * (sw * sw + sh * sh);

    float dc = t4 - conf_c;
    float obj_conf = dc * dc;
    float noobj_in_obj = LAMBDA_NOOBJ * conf_o * conf_o;

    float cls = 0.0f;
#pragma unroll
    for (int k = 10; k < 30; ++k) {
        float d = t[k] - p[k];
        cls += d * d;
    }

    float obj_terms = xy + wh + obj_conf + noobj_in_obj + cls;

    float d4 = t4 - p[4], d9 = t4 - p[9];
    float noobj_terms = LAMBDA_NOOBJ * (d4 * d4 + d9 * d9);

    return (t4 == 1.0f) ? obj_terms : noobj_terms;
}

__global__ __launch_bounds__(THREADS, 2) void yolo_loss_main(
    const float4* __restrict__ tv, const float4* __restrict__ pv,
    float* __restrict__ ws, int npairs) {
    const int pair = blockIdx.x * THREADS + threadIdx.x;

    float v = 0.0f;
    if (pair < npairs) {
        const float4* tg = tv + (size_t)pair * 15;
        const float4* pg = pv + (size_t)pair * 15;
        // 30 independent 16-B loads, all issued before any use.
        float4 tb[15], pb[15];
#pragma unroll
        for (int j = 0; j < 15; ++j) tb[j] = tg[j];
#pragma unroll
        for (int j = 0; j < 15; ++j) pb[j] = pg[j];
        const float* tf = (const float*)tb;
        const float* pf = (const float*)pb;
        v = cell_loss(tf, pf) + cell_loss(tf + 30, pf + 30);
    }

    // wave64 reduction
#pragma unroll
    for (int off = 32; off > 0; off >>= 1)
        v += __shfl_down(v, off, 64);

    // block reduction -> one plain store per block (no same-address atomics)
    __shared__ float part[THREADS / 64];
    if ((threadIdx.x & 63) == 0) part[threadIdx.x >> 6] = v;
    __syncthreads();
    if (threadIdx.x == 0) {
        float s = 0.0f;
#pragma unroll
        for (int w = 0; w < THREADS / 64; ++w) s += part[w];
        ws[blockIdx.x] = s;
    }
}

__global__ __launch_bounds__(256) void yolo_loss_finish(
    const float* __restrict__ ws, float* __restrict__ out,
    int nblocks, float inv_batch) {
    float v = 0.0f;
    for (int i = threadIdx.x; i < nblocks; i += 256) v += ws[i];
#pragma unroll
    for (int off = 32; off > 0; off >>= 1)
        v += __shfl_down(v, off, 64);
    __shared__ float part[4];
    if ((threadIdx.x & 63) == 0) part[threadIdx.x >> 6] = v;
    __syncthreads();
    if (threadIdx.x == 0)
        out[0] = (part[0] + part[1] + part[2] + part[3]) * inv_batch;
}

extern "C" void kernel_launch(void* const* d_in, const int* in_sizes, int n_in,
                              void* d_out, int out_size, void* d_ws, size_t ws_size,
                              hipStream_t stream) {
    const float* t = (const float*)d_in[0];  // y_trues
    const float* p = (const float*)d_in[1];  // y_preds
    float* out = (float*)d_out;
    float* ws = (float*)d_ws;

    const int total = in_sizes[0];            // 24,084,480 floats
    const int cells = total / 30;             // 802,816
    const int npairs = cells / 2;             // 401,408
    const int batch = cells / 49;             // 16,384
    const float inv_batch = 1.0f / (float)batch;

    // 1 pair per thread: 1568 blocks x 256 threads = 401,408 exactly.
    const int blocks = (npairs + THREADS - 1) / THREADS;

    yolo_loss_main<<<blocks, THREADS, 0, stream>>>(
        (const float4*)t, (const float4*)p, ws, npairs);
    yolo_loss_finish<<<1, 256, 0, stream>>>(ws, out, blocks, inv_batch);
}